// Round 13
// baseline (29.435 us; speedup 1.0000x reference)
//
#include <hip/hip_runtime.h>
#include <hip/hip_bf16.h>
#include <math.h>

#define KN 8192
#define DEG 32
#define EE (KN*DEG)

// VAR = float32(10^(-19.9) * 5000000 / 10)
#define VAR_F 6.294627058970831e-15f

typedef __attribute__((ext_vector_type(8)))  short bf16x8;
typedef __attribute__((ext_vector_type(16))) float f32x16;

static __device__ __forceinline__ short bf_hi(float f) {
    __hip_bfloat16 h = __float2bfloat16(f);
    return __builtin_bit_cast(short, h);
}
static __device__ __forceinline__ float bf_f(short s) {
    __hip_bfloat16 h = __builtin_bit_cast(__hip_bfloat16, s);
    return __bfloat162float(h);
}

// async global->LDS DMA: dest = wave-uniform base + lane*16, src per-lane.
static __device__ __forceinline__ void gl16(const float* src, float* lds) {
    __builtin_amdgcn_global_load_lds(
        (const __attribute__((address_space(1))) void*)src,
        (__attribute__((address_space(3))) void*)lds, 16, 0, 0);
}

// Kernel 1: fused 3x conv + head + H-row gather. ONE wave per block/node.
// R12's verified structure + Wm2 staged via 4x global_load_lds dwordx4
// (replaces 16 scalar VMEM loads + 16 VGPRs of wm2f; B-fragments convert
// from LDS, 2-way bank alias = free). XCD-contiguous node remap kept:
// k = (bid&7)*1024 + (bid>>3) gives each XCD a contiguous weight window.
// msg GEMM via mfma_f32_32x32x16_bf16, 3-term hi/lo split (~fp32 precision).
__global__ __launch_bounds__(64, 4) void mpnn_fused(
    const float* __restrict__ x,
    const float* __restrict__ edge_attr,
    const float* __restrict__ H,
    const int* __restrict__ edge_index,
    const float* __restrict__ Wm1, const float* __restrict__ bm1,
    const float* __restrict__ Wm2, const float* __restrict__ bm2,
    const float* __restrict__ Wu1, const float* __restrict__ bu1,
    const float* __restrict__ Wu2, const float* __restrict__ bu2,
    const float* __restrict__ Wh1, const float* __restrict__ bh1,
    const float* __restrict__ Wh2, const float* __restrict__ bh2,
    float* __restrict__ p_ws, float* __restrict__ valid_ws,
    float* __restrict__ hv_ws)
{
    __shared__ __align__(16) float wm2_lds[1024];
    __shared__ __align__(16) float c_lds[32];
    __shared__ float xt[44];    // [0..8]=x, [9..40]=aggr
    __shared__ float ubuf[16];

    const int lane = threadIdx.x;
    const int col  = lane & 31;
    const int g    = lane >> 5;
    const int bid  = blockIdx.x;
    const int k    = ((bid & 7) << 10) + (bid >> 3);   // XCD-contiguous remap

    const int m  = lane & 15;
    const int dg = lane >> 4;        // 0..3
    const int o  = lane & 7;
    const int mg = lane >> 3;        // 0..7

    // ---- H-row gather first (longest dependent chain: dst -> H line) ----
    const int* dstp = edge_index + EE;
    const int dv = dstp[k*DEG + col];
    const float Hv    = H[(size_t)k*KN + dv];       // random 4B within row
    const float Hdiag = H[(size_t)k*KN + k];        // uniform -> 1 line

    // ---- Wm2 via async DMA (4 wide instrs instead of 16 scalar loads) ----
    {
        const float* wp = Wm2 + (size_t)k*1024;
        gl16(wp +       lane*4, wm2_lds);
        gl16(wp + 256 + lane*4, wm2_lds + 256);
        gl16(wp + 512 + lane*4, wm2_lds + 512);
        gl16(wp + 768 + lane*4, wm2_lds + 768);
    }

    // ================= flat coalesced weight loads =================
    const float a_e = edge_attr[k*32 + col];          // edge e = col

    // Wm1 flat: element 64t+lane -> (d = 2t+g, j = col). t=4,g=1 is row d=9.
    float wm1v[5];
    #pragma unroll
    for (int t = 0; t < 5; ++t) wm1v[t] = Wm1[(size_t)k*320 + t*64 + lane];

    // Wm1 row 9 in A-fragment order: j = s*16 + g*8 + i
    float w9v[16];
    {
        const float* w9p = Wm1 + (size_t)k*320 + 288;
        float4 wa = *(const float4*)(w9p + g*8);
        float4 wb = *(const float4*)(w9p + g*8 + 4);
        float4 wc = *(const float4*)(w9p + 16 + g*8);
        float4 wd = *(const float4*)(w9p + 16 + g*8 + 4);
        w9v[0]=wa.x;  w9v[1]=wa.y;  w9v[2]=wa.z;  w9v[3]=wa.w;
        w9v[4]=wb.x;  w9v[5]=wb.y;  w9v[6]=wb.z;  w9v[7]=wb.w;
        w9v[8]=wc.x;  w9v[9]=wc.y;  w9v[10]=wc.z; w9v[11]=wc.w;
        w9v[12]=wd.x; w9v[13]=wd.y; w9v[14]=wd.z; w9v[15]=wd.w;
    }

    const float bm1_i = bm1[k*32 + col];
    const float bm2_i = bm2[k*32 + col];

    // Wu1 flat: element 64t+lane -> (d = 4t+dg, m = lane&15); tail d=40.
    float wu1v[10];
    #pragma unroll
    for (int t = 0; t < 10; ++t) wu1v[t] = Wu1[(size_t)k*656 + t*64 + lane];
    float wu1t = 0.f;
    if (lane < 16) wu1t = Wu1[(size_t)k*656 + 640 + lane];
    const float bu1_m = bu1[k*16 + m];

    const float wu2a  = Wu2[(size_t)k*128 + (mg*2+0)*8 + o];
    const float wu2b  = Wu2[(size_t)k*128 + (mg*2+1)*8 + o];
    const float bu2_o = bu2[k*8 + o];

    // Wh1 flat: element 64t+lane -> (d = 4t+dg, m = lane&15), t=0..1.
    float wh1v[2];
    #pragma unroll
    for (int t = 0; t < 2; ++t) wh1v[t] = Wh1[(size_t)k*128 + t*64 + lane];
    const float bh1_m = bh1[k*16 + m];
    const float wh2_m = Wh2[k*16 + m];
    const float bh2_k = bh2[k];

    if (lane < 9) xt[lane] = x[(size_t)k*9 + lane];

    // stash gathered H values (frees reg, overlaps store with compute)
    if (g == 0) hv_ws[k*DEG + col] = Hv;

    // ====== B-fragment conversion from staged LDS (after DMA lands) ======
    bf16x8 Bhi[2], Blo[2];
    #pragma unroll
    for (int s = 0; s < 2; ++s) {
        #pragma unroll
        for (int i = 0; i < 8; ++i) {
            float wv = wm2_lds[(s*16 + g*8 + i)*32 + col];
            short h = bf_hi(wv);
            Bhi[s][i] = h;
            Blo[s][i] = bf_hi(wv - bf_f(h));
        }
    }

    // ================= 3x conv =================
    for (int it = 0; it < 3; ++it) {
        // c_j = bm1_j + sum_{d<9} x_d Wm1[d][j]; lane holds d = 2t+g, j=col.
        float cpart = 0.f;
        #pragma unroll
        for (int t = 0; t < 4; ++t) cpart = fmaf(xt[2*t + g], wm1v[t], cpart);
        if (g == 0) cpart = fmaf(xt[8], wm1v[4], cpart);
        float c = bm1_i + cpart + __shfl_xor(cpart, 32);
        if (g == 0) c_lds[col] = c;

        // A frags: A[e=col][kk=s*16+g*8+i] = relu(c_j + a_e*Wm1[9][j])
        const float4* cb = (const float4*)c_lds;
        float4 q0 = cb[g*2 + 0];
        float4 q1 = cb[g*2 + 1];
        float4 q2 = cb[4 + g*2 + 0];
        float4 q3 = cb[4 + g*2 + 1];
        float cv[16] = {q0.x,q0.y,q0.z,q0.w, q1.x,q1.y,q1.z,q1.w,
                        q2.x,q2.y,q2.z,q2.w, q3.x,q3.y,q3.z,q3.w};
        bf16x8 Ahi[2], Alo[2];
        #pragma unroll
        for (int s = 0; s < 2; ++s) {
            #pragma unroll
            for (int i = 0; i < 8; ++i) {
                int t = s*8 + i;
                float hv = fmaxf(fmaf(a_e, w9v[t], cv[t]), 0.f);
                short h = bf_hi(hv);
                Ahi[s][i] = h;
                Alo[s][i] = bf_hi(hv - bf_f(h));
            }
        }

        // msg GEMM: D[e][i] = sum_j h[e][j] Wm2[j][i]
        f32x16 acc;
        #pragma unroll
        for (int rr = 0; rr < 16; ++rr) acc[rr] = 0.f;
        #pragma unroll
        for (int s = 0; s < 2; ++s) {
            acc = __builtin_amdgcn_mfma_f32_32x32x16_bf16(Ahi[s], Bhi[s], acc, 0, 0, 0);
            acc = __builtin_amdgcn_mfma_f32_32x32x16_bf16(Ahi[s], Blo[s], acc, 0, 0, 0);
            acc = __builtin_amdgcn_mfma_f32_32x32x16_bf16(Alo[s], Bhi[s], acc, 0, 0, 0);
        }

        // aggr_i = sum_e relu(bm2_i + D[e][i])
        float ag = 0.f;
        #pragma unroll
        for (int rr = 0; rr < 16; ++rr) ag += fmaxf(acc[rr] + bm2_i, 0.f);
        ag += __shfl_xor(ag, 32);
        if (g == 0) xt[9 + col] = ag;

        // u_m = relu(bu1_m + sum_{d<41} t_d Wu1[d][m]); lane holds d = 4t+dg.
        float up = 0.f;
        #pragma unroll
        for (int t = 0; t < 10; ++t) up = fmaf(xt[4*t + dg], wu1v[t], up);
        up = fmaf(xt[40], wu1t, up);             // wu1t==0 for lane>=16
        up += __shfl_xor(up, 16);
        up += __shfl_xor(up, 32);
        float u = fmaxf(up + bu1_m, 0.f);
        if (lane < 16) ubuf[lane] = u;

        // comb_o = relu(bu2_o + sum_m u_m Wu2[m][o])
        float cp = wu2a * ubuf[mg*2] + wu2b * ubuf[mg*2 + 1];
        cp += __shfl_xor(cp, 8);
        cp += __shfl_xor(cp, 16);
        cp += __shfl_xor(cp, 32);
        float comb = fmaxf(cp + bu2_o, 0.f);
        if (lane < 8) xt[1 + lane] = comb;   // x_new = [x0, comb]
    }

    // ================= head =================
    float hp = fmaf(xt[1 + dg], wh1v[0], 0.f);
    hp = fmaf(xt[1 + 4 + dg], wh1v[1], hp);
    hp += __shfl_xor(hp, 16);
    hp += __shfl_xor(hp, 32);
    float hh = fmaxf(hp + bh1_m, 0.f);
    float pp = hh * wh2_m;
    pp += __shfl_xor(pp, 1);
    pp += __shfl_xor(pp, 2);
    pp += __shfl_xor(pp, 4);
    pp += __shfl_xor(pp, 8);
    float z = pp + bh2_k;
    float p = 1.f / (1.f + expf(-z));
    if (lane == 0) {
        p_ws[k] = p;
        valid_ws[k] = p * Hdiag;
    }
}

// Kernel 2b: interference reduce from compact buffers, vectorized.
// 8 lanes per node, 4 edges per lane via int4/float4; 32 nodes per block.
__global__ __launch_bounds__(256) void mpnn_interf(
    const int* __restrict__ edge_index,
    const float* __restrict__ p_ws,
    const float* __restrict__ valid_ws,
    const float* __restrict__ hv_ws,
    float* __restrict__ out)
{
    const int tid = threadIdx.x;
    const int s   = blockIdx.x * 32 + (tid >> 3);
    const int e4  = tid & 7;
    const int* dstp = edge_index + EE;

    int4   d4 = ((const int4*)  (dstp  + s*DEG))[e4];
    float4 h4 = ((const float4*)(hv_ws + s*DEG))[e4];
    float part = p_ws[d4.x] * h4.x + p_ws[d4.y] * h4.y
               + p_ws[d4.z] * h4.z + p_ws[d4.w] * h4.w;
    part += __shfl_xor(part, 1);
    part += __shfl_xor(part, 2);
    part += __shfl_xor(part, 4);
    if (e4 == 0) {
        float interf = part + VAR_F;
        out[s] = -log1pf(valid_ws[s] / interf) * 1.4426950408889634f;
    }
}

extern "C" void kernel_launch(void* const* d_in, const int* in_sizes, int n_in,
                              void* d_out, int out_size, void* d_ws, size_t ws_size,
                              hipStream_t stream) {
    const float* x         = (const float*)d_in[0];
    const float* edge_attr = (const float*)d_in[1];
    const float* H         = (const float*)d_in[2];
    const int*   edge_idx  = (const int*)  d_in[3];
    const float* Wm1 = (const float*)d_in[4];
    const float* bm1 = (const float*)d_in[5];
    const float* Wm2 = (const float*)d_in[6];
    const float* bm2 = (const float*)d_in[7];
    const float* Wu1 = (const float*)d_in[8];
    const float* bu1 = (const float*)d_in[9];
    const float* Wu2 = (const float*)d_in[10];
    const float* bu2 = (const float*)d_in[11];
    const float* Wh1 = (const float*)d_in[12];
    const float* bh1 = (const float*)d_in[13];
    const float* Wh2 = (const float*)d_in[14];
    const float* bh2 = (const float*)d_in[15];
    float* out = (float*)d_out;

    float* p_ws     = (float*)d_ws;            // KN
    float* valid_ws = p_ws + KN;               // KN
    float* hv_ws    = valid_ws + KN;           // KN*DEG

    mpnn_fused<<<KN, 64, 0, stream>>>(x, edge_attr, H, edge_idx,
                                      Wm1, bm1, Wm2, bm2,
                                      Wu1, bu1, Wu2, bu2, Wh1, bh1, Wh2, bh2,
                                      p_ws, valid_ws, hv_ws);
    mpnn_interf<<<KN/32, 256, 0, stream>>>(edge_idx, p_ws, valid_ws,
                                           hv_ws, out);
}

// Round 14
// 28.638 us; speedup vs baseline: 1.0278x; 1.0278x over previous
//
#include <hip/hip_runtime.h>
#include <hip/hip_bf16.h>
#include <math.h>

#define KN 8192
#define DEG 32
#define EE (KN*DEG)

// VAR = float32(10^(-19.9) * 5000000 / 10)
#define VAR_F 6.294627058970831e-15f

typedef __attribute__((ext_vector_type(8)))  short bf16x8;
typedef __attribute__((ext_vector_type(16))) float f32x16;

static __device__ __forceinline__ short bf_hi(float f) {
    __hip_bfloat16 h = __float2bfloat16(f);
    return __builtin_bit_cast(short, h);
}
static __device__ __forceinline__ float bf_f(short s) {
    __hip_bfloat16 h = __builtin_bit_cast(__hip_bfloat16, s);
    return __bfloat162float(h);
}

// Kernel 1: fused 3x conv + head + H-row gather. ONE wave per block/node.
// R8 structure (all loads issued up front, register-resident weights,
// wave-private LDS, no barriers) + XCD-contiguous node remap:
// blockIdx round-robins XCDs (bid%8 = XCD), so k = (bid&7)*1024 + (bid>>3)
// gives each XCD a CONTIGUOUS 1024-node weight window (~12 MB) -> DRAM
// row-buffer / L2 locality for the streamed weights. (Measured: -1.2us.)
// msg GEMM via mfma_f32_32x32x16_bf16, 3-term hi/lo split (~fp32 precision).
__global__ __launch_bounds__(64, 4) void mpnn_fused(
    const float* __restrict__ x,
    const float* __restrict__ edge_attr,
    const float* __restrict__ H,
    const int* __restrict__ edge_index,
    const float* __restrict__ Wm1, const float* __restrict__ bm1,
    const float* __restrict__ Wm2, const float* __restrict__ bm2,
    const float* __restrict__ Wu1, const float* __restrict__ bu1,
    const float* __restrict__ Wu2, const float* __restrict__ bu2,
    const float* __restrict__ Wh1, const float* __restrict__ bh1,
    const float* __restrict__ Wh2, const float* __restrict__ bh2,
    float* __restrict__ p_ws, float* __restrict__ valid_ws,
    float* __restrict__ hv_ws)
{
    __shared__ __align__(16) float c_lds[32];
    __shared__ float xt[44];    // [0..8]=x, [9..40]=aggr
    __shared__ float ubuf[16];

    const int lane = threadIdx.x;
    const int col  = lane & 31;
    const int g    = lane >> 5;
    const int bid  = blockIdx.x;
    const int k    = ((bid & 7) << 10) + (bid >> 3);   // XCD-contiguous remap

    const int m  = lane & 15;
    const int dg = lane >> 4;        // 0..3
    const int o  = lane & 7;
    const int mg = lane >> 3;        // 0..7

    // ---- H-row gather first (longest dependent chain: dst -> H line) ----
    const int* dstp = edge_index + EE;
    const int dv = dstp[k*DEG + col];
    const float Hv    = H[(size_t)k*KN + dv];       // random 4B within row
    const float Hdiag = H[(size_t)k*KN + k];        // uniform -> 1 line

    // ================= flat coalesced weight loads =================
    const float a_e = edge_attr[k*32 + col];          // edge e = col

    // Wm1 flat: element 64t+lane -> (d = 2t+g, j = col). t=4,g=1 is row d=9.
    float wm1v[5];
    #pragma unroll
    for (int t = 0; t < 5; ++t) wm1v[t] = Wm1[(size_t)k*320 + t*64 + lane];

    // Wm1 row 9 in A-fragment order: j = s*16 + g*8 + i
    float w9v[16];
    {
        const float* w9p = Wm1 + (size_t)k*320 + 288;
        float4 wa = *(const float4*)(w9p + g*8);
        float4 wb = *(const float4*)(w9p + g*8 + 4);
        float4 wc = *(const float4*)(w9p + 16 + g*8);
        float4 wd = *(const float4*)(w9p + 16 + g*8 + 4);
        w9v[0]=wa.x;  w9v[1]=wa.y;  w9v[2]=wa.z;  w9v[3]=wa.w;
        w9v[4]=wb.x;  w9v[5]=wb.y;  w9v[6]=wb.z;  w9v[7]=wb.w;
        w9v[8]=wc.x;  w9v[9]=wc.y;  w9v[10]=wc.z; w9v[11]=wc.w;
        w9v[12]=wd.x; w9v[13]=wd.y; w9v[14]=wd.z; w9v[15]=wd.w;
    }

    // Wm2 in B-fragment order (2 coalesced 128B rows per instr)
    float wm2f[16];
    #pragma unroll
    for (int s = 0; s < 2; ++s)
        #pragma unroll
        for (int i = 0; i < 8; ++i)
            wm2f[s*8+i] = Wm2[(size_t)k*1024 + (s*16 + g*8 + i)*32 + col];

    const float bm1_i = bm1[k*32 + col];
    const float bm2_i = bm2[k*32 + col];

    // Wu1 flat: element 64t+lane -> (d = 4t+dg, m = lane&15); tail d=40.
    float wu1v[10];
    #pragma unroll
    for (int t = 0; t < 10; ++t) wu1v[t] = Wu1[(size_t)k*656 + t*64 + lane];
    float wu1t = 0.f;
    if (lane < 16) wu1t = Wu1[(size_t)k*656 + 640 + lane];
    const float bu1_m = bu1[k*16 + m];

    const float wu2a  = Wu2[(size_t)k*128 + (mg*2+0)*8 + o];
    const float wu2b  = Wu2[(size_t)k*128 + (mg*2+1)*8 + o];
    const float bu2_o = bu2[k*8 + o];

    // Wh1 flat: element 64t+lane -> (d = 4t+dg, m = lane&15), t=0..1.
    float wh1v[2];
    #pragma unroll
    for (int t = 0; t < 2; ++t) wh1v[t] = Wh1[(size_t)k*128 + t*64 + lane];
    const float bh1_m = bh1[k*16 + m];
    const float wh2_m = Wh2[k*16 + m];
    const float bh2_k = bh2[k];

    if (lane < 9) xt[lane] = x[(size_t)k*9 + lane];

    // stash gathered H values (frees reg, overlaps store with compute)
    if (g == 0) hv_ws[k*DEG + col] = Hv;

    // ================= conversions (after loads issued) =================
    bf16x8 Bhi[2], Blo[2];
    #pragma unroll
    for (int s = 0; s < 2; ++s) {
        #pragma unroll
        for (int i = 0; i < 8; ++i) {
            float wv = wm2f[s*8+i];
            short h = bf_hi(wv);
            Bhi[s][i] = h;
            Blo[s][i] = bf_hi(wv - bf_f(h));
        }
    }

    // ================= 3x conv =================
    for (int it = 0; it < 3; ++it) {
        // c_j = bm1_j + sum_{d<9} x_d Wm1[d][j]; lane holds d = 2t+g, j=col.
        float cpart = 0.f;
        #pragma unroll
        for (int t = 0; t < 4; ++t) cpart = fmaf(xt[2*t + g], wm1v[t], cpart);
        if (g == 0) cpart = fmaf(xt[8], wm1v[4], cpart);
        float c = bm1_i + cpart + __shfl_xor(cpart, 32);
        if (g == 0) c_lds[col] = c;

        // A frags: A[e=col][kk=s*16+g*8+i] = relu(c_j + a_e*Wm1[9][j])
        const float4* cb = (const float4*)c_lds;
        float4 q0 = cb[g*2 + 0];
        float4 q1 = cb[g*2 + 1];
        float4 q2 = cb[4 + g*2 + 0];
        float4 q3 = cb[4 + g*2 + 1];
        float cv[16] = {q0.x,q0.y,q0.z,q0.w, q1.x,q1.y,q1.z,q1.w,
                        q2.x,q2.y,q2.z,q2.w, q3.x,q3.y,q3.z,q3.w};
        bf16x8 Ahi[2], Alo[2];
        #pragma unroll
        for (int s = 0; s < 2; ++s) {
            #pragma unroll
            for (int i = 0; i < 8; ++i) {
                int t = s*8 + i;
                float hv = fmaxf(fmaf(a_e, w9v[t], cv[t]), 0.f);
                short h = bf_hi(hv);
                Ahi[s][i] = h;
                Alo[s][i] = bf_hi(hv - bf_f(h));
            }
        }

        // msg GEMM: D[e][i] = sum_j h[e][j] Wm2[j][i]
        f32x16 acc;
        #pragma unroll
        for (int rr = 0; rr < 16; ++rr) acc[rr] = 0.f;
        #pragma unroll
        for (int s = 0; s < 2; ++s) {
            acc = __builtin_amdgcn_mfma_f32_32x32x16_bf16(Ahi[s], Bhi[s], acc, 0, 0, 0);
            acc = __builtin_amdgcn_mfma_f32_32x32x16_bf16(Ahi[s], Blo[s], acc, 0, 0, 0);
            acc = __builtin_amdgcn_mfma_f32_32x32x16_bf16(Alo[s], Bhi[s], acc, 0, 0, 0);
        }

        // aggr_i = sum_e relu(bm2_i + D[e][i])
        float ag = 0.f;
        #pragma unroll
        for (int rr = 0; rr < 16; ++rr) ag += fmaxf(acc[rr] + bm2_i, 0.f);
        ag += __shfl_xor(ag, 32);
        if (g == 0) xt[9 + col] = ag;

        // u_m = relu(bu1_m + sum_{d<41} t_d Wu1[d][m]); lane holds d = 4t+dg.
        float up = 0.f;
        #pragma unroll
        for (int t = 0; t < 10; ++t) up = fmaf(xt[4*t + dg], wu1v[t], up);
        up = fmaf(xt[40], wu1t, up);             // wu1t==0 for lane>=16
        up += __shfl_xor(up, 16);
        up += __shfl_xor(up, 32);
        float u = fmaxf(up + bu1_m, 0.f);
        if (lane < 16) ubuf[lane] = u;

        // comb_o = relu(bu2_o + sum_m u_m Wu2[m][o])
        float cp = wu2a * ubuf[mg*2] + wu2b * ubuf[mg*2 + 1];
        cp += __shfl_xor(cp, 8);
        cp += __shfl_xor(cp, 16);
        cp += __shfl_xor(cp, 32);
        float comb = fmaxf(cp + bu2_o, 0.f);
        if (lane < 8) xt[1 + lane] = comb;   // x_new = [x0, comb]
    }

    // ================= head =================
    float hp = fmaf(xt[1 + dg], wh1v[0], 0.f);
    hp = fmaf(xt[1 + 4 + dg], wh1v[1], hp);
    hp += __shfl_xor(hp, 16);
    hp += __shfl_xor(hp, 32);
    float hh = fmaxf(hp + bh1_m, 0.f);
    float pp = hh * wh2_m;
    pp += __shfl_xor(pp, 1);
    pp += __shfl_xor(pp, 2);
    pp += __shfl_xor(pp, 4);
    pp += __shfl_xor(pp, 8);
    float z = pp + bh2_k;
    float p = 1.f / (1.f + expf(-z));
    if (lane == 0) {
        p_ws[k] = p;
        valid_ws[k] = p * Hdiag;
    }
}

// Kernel 2b: interference reduce from compact buffers, vectorized.
// 8 lanes per node, 4 edges per lane via int4/float4; 32 nodes per block.
__global__ __launch_bounds__(256) void mpnn_interf(
    const int* __restrict__ edge_index,
    const float* __restrict__ p_ws,
    const float* __restrict__ valid_ws,
    const float* __restrict__ hv_ws,
    float* __restrict__ out)
{
    const int tid = threadIdx.x;
    const int s   = blockIdx.x * 32 + (tid >> 3);
    const int e4  = tid & 7;
    const int* dstp = edge_index + EE;

    int4   d4 = ((const int4*)  (dstp  + s*DEG))[e4];
    float4 h4 = ((const float4*)(hv_ws + s*DEG))[e4];
    float part = p_ws[d4.x] * h4.x + p_ws[d4.y] * h4.y
               + p_ws[d4.z] * h4.z + p_ws[d4.w] * h4.w;
    part += __shfl_xor(part, 1);
    part += __shfl_xor(part, 2);
    part += __shfl_xor(part, 4);
    if (e4 == 0) {
        float interf = part + VAR_F;
        out[s] = -log1pf(valid_ws[s] / interf) * 1.4426950408889634f;
    }
}

extern "C" void kernel_launch(void* const* d_in, const int* in_sizes, int n_in,
                              void* d_out, int out_size, void* d_ws, size_t ws_size,
                              hipStream_t stream) {
    const float* x         = (const float*)d_in[0];
    const float* edge_attr = (const float*)d_in[1];
    const float* H         = (const float*)d_in[2];
    const int*   edge_idx  = (const int*)  d_in[3];
    const float* Wm1 = (const float*)d_in[4];
    const float* bm1 = (const float*)d_in[5];
    const float* Wm2 = (const float*)d_in[6];
    const float* bm2 = (const float*)d_in[7];
    const float* Wu1 = (const float*)d_in[8];
    const float* bu1 = (const float*)d_in[9];
    const float* Wu2 = (const float*)d_in[10];
    const float* bu2 = (const float*)d_in[11];
    const float* Wh1 = (const float*)d_in[12];
    const float* bh1 = (const float*)d_in[13];
    const float* Wh2 = (const float*)d_in[14];
    const float* bh2 = (const float*)d_in[15];
    float* out = (float*)d_out;

    float* p_ws     = (float*)d_ws;            // KN
    float* valid_ws = p_ws + KN;               // KN
    float* hv_ws    = valid_ws + KN;           // KN*DEG

    mpnn_fused<<<KN, 64, 0, stream>>>(x, edge_attr, H, edge_idx,
                                      Wm1, bm1, Wm2, bm2,
                                      Wu1, bu1, Wu2, bu2, Wh1, bh1, Wh2, bh2,
                                      p_ws, valid_ws, hv_ws);
    mpnn_interf<<<KN/32, 256, 0, stream>>>(edge_idx, p_ws, valid_ws,
                                           hv_ws, out);
}